// Round 11
// baseline (473.541 us; speedup 1.0000x reference)
//
#include <hip/hip_runtime.h>
#include <cstdint>
#include <cstddef>

// PiFormerBlock, MFMA fp16, round 19.
//   x = x + linattn(LN1(x)) @ wo ;  x = x + gelu_lut(LN2(x) @ w1) @ w2
// Round-19 (round-18 = 429.5us frozen otherwise): w2 moved to the FAT tile.
//   Ledger fix: round-10 top-5 (all 84.9us, LDS 65536) is w2 across bench
//   iterations -- wo is only 17.2 GFLOP (~25us) and never charted. w2 is
//   the largest single dispatch (20% of total).
//   w2 fat config: 256x128 tile, grid (8,32) = 256 blocks = 1 blk/CU.
//   Per-CU pipe model: LDS 96 reads x 8cyc + DMA 384 = 1152 cyc/K-tile vs
//   MFMA floor 1242 -> balanced; per-CU DMA volume halves vs the 2-blk
//   BK=128 path. Risk: 4 waves/CU on the barrier drain (m132 precedent);
//   if >=85us, revert + declare structural roofline.
//   Fat kernel gains EP=2 (out = R + v, fp32) and now has a distinct symbol
//   per GEMM: qkv=fat<4>, w1=fat<3>, w2=fat<2>, wo=mfma_gemm<2,128>.
//
// ws layout (bytes):
//   0      xn    [8192x1024] fp16 (16MB)  (reused as attn out)
//   32MB   phiq  fp16 (16MB) \
//   48MB   phik  fp16 (16MB)  >-- contiguous qkv slab; later overlaid by
//   64MB   vbuf  fp16 (16MB) /    ffn fp16 [8192x4096] (64MB @ 32MB)
//   96MB   w1T   fp16 (8MB) | 104MB w2T fp16 (8MB) | 128MB woT fp16 (2MB)
// d_out scratch (dead before wo-GEMM writes it):
//   0MB wqkvT (6MB) | 6MB kv partials (8.5MB) | 24MB kvT16 (512KB) | 25MB z

#define D_MODEL 1024
#define SEQ     2048
#define BATCH   4
#define NTOK    8192
#define NHEADS  16
#define DH      64
#define DFF     4096
#define KVCH    8
#define CHROWS  (SEQ / KVCH)
#define PSTRIDE 4160

typedef _Float16 half8 __attribute__((ext_vector_type(8)));
typedef float f32x4 __attribute__((ext_vector_type(4)));
typedef unsigned int u32x4 __attribute__((ext_vector_type(4)));

__device__ __forceinline__ unsigned short f2h(float x) {
  _Float16 h = (_Float16)x;
  union { _Float16 h; unsigned short u; } c; c.h = h; return c.u;
}
__device__ __forceinline__ float h2f(unsigned short u) {
  union { unsigned short u; _Float16 h; } c; c.u = u; return (float)c.h;
}

__device__ __forceinline__ float phi_act(float x) {
  return x > 0.f ? x + 1.f : expf(x);
}

__device__ __forceinline__ float gelu_exact(float v) {
  float c = 0.7978845608028654f;
  float t = tanhf(c * (v + 0.044715f * v * v * v));
  return 0.5f * v * (1.f + t);
}

__device__ __forceinline__ void gl_lds16(const void* g, void* l) {
  __builtin_amdgcn_global_load_lds(
      (const __attribute__((address_space(1))) unsigned int*)g,
      (__attribute__((address_space(3))) unsigned int*)l, 16, 0, 0);
}

// ---------------- transpose-convert body: W fp32 [K,N] -> WT fp16 [N,K] ----
__device__ __forceinline__ void convT_body(const float* __restrict__ W,
                                           unsigned short* __restrict__ WT,
                                           int K, int N, int bx, int by, int t) {
  __shared__ float tile[64][65];
  int kb = by << 6, nb = bx << 6;
  int rr = t >> 4, cc = (t & 15) << 2;
#pragma unroll
  for (int i = 0; i < 4; ++i) {
    int r = rr + (i << 4);
    float4 v = *(const float4*)(W + (size_t)(kb + r) * N + nb + cc);
    tile[r][cc] = v.x; tile[r][cc + 1] = v.y; tile[r][cc + 2] = v.z; tile[r][cc + 3] = v.w;
  }
  __syncthreads();
#pragma unroll
  for (int i = 0; i < 4; ++i) {
    int n = rr + (i << 4);
    ushort4 o;
    o.x = f2h(tile[cc + 0][n]); o.y = f2h(tile[cc + 1][n]);
    o.z = f2h(tile[cc + 2][n]); o.w = f2h(tile[cc + 3][n]);
    *(ushort4*)(WT + (size_t)(nb + n) * K + kb + cc) = o;
  }
}

// ---------------- LayerNorm body -> fp16 -----------------------------------
__device__ __forceinline__ void ln_body(const float* __restrict__ X,
                                        const float* __restrict__ g,
                                        const float* __restrict__ b,
                                        unsigned short* __restrict__ Y,
                                        int tok, int t) {
  const float4* xr = (const float4*)(X + (size_t)tok * D_MODEL);
  float4 v = xr[t];
  float s  = v.x + v.y + v.z + v.w;
  float s2 = v.x * v.x + v.y * v.y + v.z * v.z + v.w * v.w;
#pragma unroll
  for (int o = 32; o > 0; o >>= 1) {
    s  += __shfl_down(s, o);
    s2 += __shfl_down(s2, o);
  }
  __shared__ float red[8];
  __shared__ float mu_s, rs_s;
  int wid = t >> 6;
  if ((t & 63) == 0) { red[wid] = s; red[wid + 4] = s2; }
  __syncthreads();
  if (t == 0) {
    float ts  = red[0] + red[1] + red[2] + red[3];
    float ts2 = red[4] + red[5] + red[6] + red[7];
    float mu  = ts * (1.f / D_MODEL);
    float var = ts2 * (1.f / D_MODEL) - mu * mu;
    mu_s = mu;
    rs_s = rsqrtf(var + 1e-5f);
  }
  __syncthreads();
  float mu = mu_s, rs = rs_s;
  float4 gv = ((const float4*)g)[t];
  float4 bv = ((const float4*)b)[t];
  ushort4 hv;
  hv.x = f2h((v.x - mu) * rs * gv.x + bv.x);
  hv.y = f2h((v.y - mu) * rs * gv.y + bv.y);
  hv.z = f2h((v.z - mu) * rs * gv.z + bv.z);
  hv.w = f2h((v.w - mu) * rs * gv.w + bv.w);
  ((ushort4*)(Y + (size_t)tok * D_MODEL))[t] = hv;
}

// ---------------- prep: 6 weight transposes + LN1 in one launch ------------
__global__ __launch_bounds__(256) void prep_kernel(
    const float* __restrict__ wq, const float* __restrict__ wk,
    const float* __restrict__ wv, const float* __restrict__ wo,
    const float* __restrict__ w1, const float* __restrict__ w2,
    const float* __restrict__ x, const float* __restrict__ g,
    const float* __restrict__ b,
    unsigned short* __restrict__ wqkvT, unsigned short* __restrict__ woT,
    unsigned short* __restrict__ w1T, unsigned short* __restrict__ w2T,
    unsigned short* __restrict__ xn) {
  int f = blockIdx.x;
  int t = threadIdx.x;
  if (f < 1024) {
    int job = f >> 8, r = f & 255;
    const float* W = (job == 0) ? wq : (job == 1) ? wk : (job == 2) ? wv : wo;
    unsigned short* D = (job == 3) ? woT
                                   : wqkvT + (size_t)job * D_MODEL * D_MODEL;
    convT_body(W, D, D_MODEL, D_MODEL, r & 15, r >> 4, t);
  } else if (f < 2048) {
    int r = f - 1024;
    convT_body(w1, w1T, D_MODEL, DFF, r & 63, r >> 6, t);
  } else if (f < 3072) {
    int r = f - 2048;
    convT_body(w2, w2T, DFF, D_MODEL, r & 15, r >> 4, t);
  } else {
    ln_body(x, g, b, xn, f - 3072, t);
  }
}

// ---------------- standalone LN (for LN2) ----------------------------------
__global__ __launch_bounds__(256) void ln_kernel(const float* __restrict__ X,
                                                 const float* __restrict__ g,
                                                 const float* __restrict__ b,
                                                 unsigned short* __restrict__ Y) {
  ln_body(X, g, b, Y, blockIdx.x, threadIdx.x);
}

// ---------------- MFMA GEMM: C[M,N] = A[M,K] @ BT[N,K]^T (fp16 in) ---------
// 128x128 tile, 4 waves @ 64x64. Kept for wo (N=1024, K=1024).
template <int EP, int BK>
__global__ __launch_bounds__(256, (BK == 64) ? 4 : 2) void mfma_gemm(
    const unsigned short* __restrict__ A,
    const unsigned short* __restrict__ BT,
    void* Cv, const float* R, int N, int K) {
  constexpr int SEGS = BK / 8;
  constexpr int RPC  = 64 / SEGS;
  constexpr int NJ   = 32 / RPC;
  __shared__ unsigned short smem[2 * 128 * BK];
  __shared__ float gtab[EP == 3 ? 256 : 1];
  unsigned short* sA = smem;
  unsigned short* sB = smem + 128 * BK;

  int t = threadIdx.x;
  if (EP == 3) gtab[t & 255] = gelu_exact((float)((t & 255) - 128) * 0.1f);

  int bm, bn;
  {
    int L = blockIdx.y * gridDim.x + blockIdx.x;
    if ((gridDim.y & 7) == 0) {
      int xcd = L & 7, wi = L >> 3;
      int mPerX = gridDim.y >> 3;
      bm = xcd * mPerX + wi / gridDim.x;
      bn = wi % gridDim.x;
    } else {
      bn = blockIdx.x; bm = blockIdx.y;
    }
  }

  int w = t >> 6, l = t & 63;
  int lrow = l / SEGS;
  int lseg = l & (SEGS - 1);
  int m0 = bm << 7;
  int n0 = bn << 7;
  size_t strideB = (size_t)K * 2;

  const char* gA[NJ]; const char* gB[NJ];
  int ldsOff[NJ];
#pragma unroll
  for (int j = 0; j < NJ; ++j) {
    int row = (w << 5) + j * RPC + lrow;
    int gso = (lseg ^ (row & 7)) << 4;
    gA[j] = (const char*)A + (size_t)(m0 + row) * strideB + gso;
    gB[j] = (const char*)BT + (size_t)(n0 + row) * strideB + gso;
    ldsOff[j] = ((w << 5) + j * RPC) * BK;
  }

  int wm = w >> 1, wn = w & 1;
  int m16 = l & 15, qd = l >> 4;

  f32x4 acc[4][4];
#pragma unroll
  for (int i = 0; i < 4; ++i)
#pragma unroll
    for (int j = 0; j < 4; ++j) acc[i][j] = (f32x4){0.f, 0.f, 0.f, 0.f};

  for (int k0 = 0; k0 < K; k0 += BK) {
    size_t kb = (size_t)k0 * 2;
#pragma unroll
    for (int j = 0; j < NJ; ++j) {
      gl_lds16(gA[j] + kb, sA + ldsOff[j]);
      gl_lds16(gB[j] + kb, sB + ldsOff[j]);
    }
    __syncthreads();
#pragma unroll
    for (int kk = 0; kk < BK / 32; ++kk) {
      int ksb = (kk << 2) + qd;
      half8 af[4], bf[4];
#pragma unroll
      for (int mt = 0; mt < 4; ++mt) {
        int r = (wm << 6) + (mt << 4) + m16;
        int slot = ksb ^ (r & 7);
        af[mt] = *(const half8*)(sA + r * BK + (slot << 3));
      }
#pragma unroll
      for (int nt = 0; nt < 4; ++nt) {
        int r = (wn << 6) + (nt << 4) + m16;
        int slot = ksb ^ (r & 7);
        bf[nt] = *(const half8*)(sB + r * BK + (slot << 3));
      }
#pragma unroll
      for (int mt = 0; mt < 4; ++mt)
#pragma unroll
        for (int nt = 0; nt < 4; ++nt)
          acc[mt][nt] = __builtin_amdgcn_mfma_f32_16x16x32_f16(af[mt], bf[nt], acc[mt][nt], 0, 0, 0);
    }
    __syncthreads();
  }

  int colBase = n0 + (wn << 6) + m16;
#pragma unroll
  for (int mt = 0; mt < 4; ++mt) {
    int rBase = m0 + (wm << 6) + (mt << 4) + (qd << 2);
#pragma unroll
    for (int nt = 0; nt < 4; ++nt) {
      int col = colBase + (nt << 4);
#pragma unroll
      for (int i = 0; i < 4; ++i) {
        float v = acc[mt][nt][i];
        size_t idx = (size_t)(rBase + i) * N + col;
        if (EP == 2)      ((float*)Cv)[idx] = R[idx] + v;
        else if (EP == 3) {
          float r = rintf(v / 0.1f);
          int iq = (int)r + 128;
          iq = iq < 0 ? 0 : (iq > 255 ? 255 : iq);
          ((unsigned short*)Cv)[idx] = f2h(gtab[iq]);
        } else          ((float*)Cv)[idx] = v;
      }
    }
  }
}

// ---------------- FAT MFMA GEMM: 256x128 tile, 4 waves @ 128x64 ------------
// 24 b128 per 64 MFMA = 0.375 b128/MFMA (-25% LDS/FLOP vs 64x64 wave tile).
// acc 8x4 (~200 VGPR, launch_bounds(256,2)); LDS 48KB. BK=64.
// EP: 2 = out = R + v fp32 (w2) | 3 gelu-LUT (w1) | 4 fused qkv.
template <int EP>
__global__ __launch_bounds__(256, 2) void mfma_gemm_fat(
    const unsigned short* __restrict__ A,
    const unsigned short* __restrict__ BT,
    void* Cv, const float* R, int N, int K) {
  constexpr int BK = 64;
  __shared__ unsigned short sA[256 * BK];   // 32 KB
  __shared__ unsigned short sB[128 * BK];   // 16 KB
  __shared__ float gtab[EP == 3 ? 256 : 1];

  int t = threadIdx.x;
  if (EP == 3) gtab[t & 255] = gelu_exact((float)((t & 255) - 128) * 0.1f);

  int bm, bn;
  {
    int L = blockIdx.y * gridDim.x + blockIdx.x;
    if ((gridDim.y & 7) == 0) {                 // NTOK/256 = 32 -> true
      int xcd = L & 7, wi = L >> 3;
      int mPerX = gridDim.y >> 3;
      bm = xcd * mPerX + wi / gridDim.x;
      bn = wi % gridDim.x;
    } else {
      bn = blockIdx.x; bm = blockIdx.y;
    }
  }
  int m0 = bm << 8, n0 = bn << 7;

  int w = t >> 6, l = t & 63;
  int lrow = l >> 3;          // SEGS = 8
  int lseg = l & 7;
  size_t strideB = (size_t)K * 2;
  size_t rstep8 = (size_t)8 * strideB;        // 8 rows of global stride

  // staging bases: wave w owns A rows [w*64, +64) (8 calls), B rows [w*32,+32) (4)
  int rowA0 = (w << 6) + lrow;
  int rowB0 = (w << 5) + lrow;
  const char* gA0 = (const char*)A  + (size_t)(m0 + rowA0) * strideB + ((lseg ^ (rowA0 & 7)) << 4);
  const char* gB0 = (const char*)BT + (size_t)(n0 + rowB0) * strideB + ((lseg ^ (rowB0 & 7)) << 4);
  // (rowA0+8j)&7 == rowA0&7 -> same swizzled seg offset for all j
  int ldsA0 = ((w << 6)) * BK;                // shorts; +j*512
  int ldsB0 = ((w << 5)) * BK;

  int wm = w >> 1, wn = w & 1;
  int m16 = l & 15, qd = l >> 4;

  f32x4 acc[8][4];
#pragma unroll
  for (int i = 0; i < 8; ++i)
#pragma unroll
    for (int j = 0; j < 4; ++j) acc[i][j] = (f32x4){0.f, 0.f, 0.f, 0.f};

  for (int k0 = 0; k0 < K; k0 += BK) {
    size_t kb = (size_t)k0 * 2;
#pragma unroll
    for (int j = 0; j < 8; ++j)
      gl_lds16(gA0 + kb + j * rstep8, sA + ldsA0 + j * 512);
#pragma unroll
    for (int j = 0; j < 4; ++j)
      gl_lds16(gB0 + kb + j * rstep8, sB + ldsB0 + j * 512);
    __syncthreads();
#pragma unroll
    for (int kk = 0; kk < 2; ++kk) {
      int ksb = (kk << 2) + qd;
      half8 af[8], bf[4];
#pragma unroll
      for (int mt = 0; mt < 8; ++mt) {
        int r = (wm << 7) + (mt << 4) + m16;
        af[mt] = *(const half8*)(sA + r * BK + ((ksb ^ (r & 7)) << 3));
      }
#pragma unroll
      for (int nt = 0; nt < 4; ++nt) {
        int r = (wn << 6) + (nt << 4) + m16;
        bf[nt] = *(const half8*)(sB + r * BK + ((ksb ^ (r & 7)) << 3));
      }
#pragma unroll
      for (int mt = 0; mt < 8; ++mt)
#pragma unroll
        for (int nt = 0; nt < 4; ++nt)
          acc[mt][nt] = __builtin_amdgcn_mfma_f32_16x16x32_f16(af[mt], bf[nt], acc[mt][nt], 0, 0, 0);
    }
    __syncthreads();
  }

  // epilogue
  int sel = n0 >> 10;                       // EP=4: 0=q 1=k 2=v
  size_t slab = (size_t)sel * ((size_t)NTOK * D_MODEL);
  int colL = (n0 & 1023) + (wn << 6) + m16;
  int colBase = n0 + (wn << 6) + m16;
#pragma unroll
  for (int mt = 0; mt < 8; ++mt) {
    int rBase = m0 + (wm << 7) + (mt << 4) + (qd << 2);
#pragma unroll
    for (int nt = 0; nt < 4; ++nt) {
#pragma unroll
      for (int i = 0; i < 4; ++i) {
        float v = acc[mt][nt][i];
        if (EP == 4) {
          if (sel < 2) v = phi_act(v);
          size_t idx = slab + (size_t)(rBase + i) * D_MODEL + colL + (nt << 4);
          ((unsigned short*)Cv)[idx] = f2h(v);
        } else if (EP == 2) {
          size_t idx = (size_t)(rBase + i) * N + colBase + (nt << 4);
          ((float*)Cv)[idx] = R[idx] + v;
        } else {  // EP == 3
          float r = rintf(v / 0.1f);
          int iq = (int)r + 128;
          iq = iq < 0 ? 0 : (iq > 255 ? 255 : iq);
          ((unsigned short*)Cv)[(size_t)(rBase + i) * N + colBase + (nt << 4)] = f2h(gtab[iq]);
        }
      }
    }
  }
}

// ---------------- stage 1: partial kv/z over an S-chunk (fp16 in) ----------
__global__ __launch_bounds__(256) void kvz_partial(const unsigned short* __restrict__ PK,
                                                   const unsigned short* __restrict__ V,
                                                   float* __restrict__ P) {
  int c = blockIdx.x, bh = blockIdx.y;
  int b = bh >> 4, h = bh & 15;
  __shared__ float pk[8][64];
  __shared__ float vv[8][64];
  int t = threadIdx.x;
  const size_t base = ((size_t)b * SEQ + (size_t)c * CHROWS) * D_MODEL + h * DH;
  int u = t & 127;
  int lrow = u >> 4;
  int lcol = (u & 15) << 2;
  bool isV = (t >= 128);
  const unsigned short* src = isV ? V : PK;
  int dkb = (t >> 4) << 2;
  int deb = (t & 15) << 2;
  float acc[4][4] = {};
  float zacc = 0.f;
  for (int s0 = 0; s0 < CHROWS; s0 += 8) {
    ushort4 ld = *(const ushort4*)(src + base + (size_t)(s0 + lrow) * D_MODEL + lcol);
    float f0 = h2f(ld.x), f1 = h2f(ld.y), f2 = h2f(ld.z), f3 = h2f(ld.w);
    __syncthreads();
    if (isV) { vv[lrow][lcol] = f0; vv[lrow][lcol+1] = f1; vv[lrow][lcol+2] = f2; vv[lrow][lcol+3] = f3; }
    else     { pk[lrow][lcol] = f0; pk[lrow][lcol+1] = f1; pk[lrow][lcol+2] = f2; pk[lrow][lcol+3] = f3; }
    __syncthreads();
#pragma unroll
    for (int ss = 0; ss < 8; ++ss) {
      float4 a  = *(const float4*)&pk[ss][dkb];
      float4 bb = *(const float4*)&vv[ss][deb];
      acc[0][0] += a.x * bb.x; acc[0][1] += a.x * bb.y; acc[0][2] += a.x * bb.z; acc[0][3] += a.x * bb.w;
      acc[1][0] += a.y * bb.x; acc[1][1] += a.y * bb.y; acc[1][2] += a.y * bb.z; acc[1][3] += a.y * bb.w;
      acc[2][0] += a.z * bb.x; acc[2][1] += a.z * bb.y; acc[2][2] += a.z * bb.z; acc[2][3] += a.z * bb.w;
      acc[3][0] += a.w * bb.x; acc[3][1] += a.w * bb.y; acc[3][2] += a.w * bb.z; acc[3][3] += a.w * bb.w;
    }
    if (t < 64) {
#pragma unroll
      for (int ss = 0; ss < 8; ++ss) zacc += pk[ss][t];
    }
  }
  float* Pb = P + ((size_t)c * 64 + bh) * PSTRIDE;
#pragma unroll
  for (int i = 0; i < 4; ++i) {
    float4 o; o.x = acc[i][0]; o.y = acc[i][1]; o.z = acc[i][2]; o.w = acc[i][3];
    *(float4*)(Pb + (size_t)(dkb + i) * DH + deb) = o;
  }
  if (t < 64) Pb[4096 + t] = zacc;
}

// ---------------- stage 2: reduce partials -> kvT fp16 [e][d] + z fp32 -----
// grid (64 bh, 4): quarter q handles elements [q*1040, (q+1)*1040).
__global__ __launch_bounds__(256) void kvz_reduce(const float* __restrict__ P,
                                                  unsigned short* __restrict__ KVT,
                                                  float* __restrict__ Z) {
  int bh = blockIdx.x;
  int q = blockIdx.y;
  int t = threadIdx.x;
  int lo = q * (PSTRIDE / 4), hi = lo + (PSTRIDE / 4);
  for (int i = lo + t; i < hi; i += 256) {
    float s = 0.f;
#pragma unroll
    for (int c = 0; c < KVCH; ++c)
      s += P[((size_t)c * 64 + bh) * PSTRIDE + i];
    if (i < 4096) {
      int d = i >> 6, e = i & 63;
      KVT[(size_t)bh * 4096 + e * 64 + d] = f2h(s);   // BT layout [e][d]
    } else {
      Z[(size_t)bh * 64 + (i - 4096)] = s;
    }
  }
}

// ---------------- attn via MFMA: out = (phiq @ kv) / (phiq.z) --------------
__global__ __launch_bounds__(256) void attn_mfma(const unsigned short* __restrict__ PQ,
                                                 const unsigned short* __restrict__ KVT,
                                                 const float* __restrict__ Z,
                                                 unsigned short* __restrict__ O) {
  __shared__ unsigned short sA[256 * 64];   // 32 KB, swizzled
  __shared__ unsigned short sB[64 * 64];    // 8 KB, swizzled
  __shared__ float zsh[64];
  __shared__ float dsh[256];
  int t = threadIdx.x;
  int tok0 = blockIdx.x << 8;
  int h = blockIdx.y;
  int b = tok0 >> 11;                       // SEQ=2048
  int bh = b * NHEADS + h;

  const unsigned short* aSrc = PQ + (size_t)tok0 * D_MODEL + h * DH;
#pragma unroll
  for (int j = 0; j < 8; ++j) {
    int id = t + (j << 8);
    int r = id >> 3, s = id & 7;
    u32x4 v = *(const u32x4*)(aSrc + (size_t)r * D_MODEL + (s << 3));
    *(u32x4*)(sA + r * 64 + ((s ^ (r & 7)) << 3)) = v;
  }
  const unsigned short* bSrc = KVT + (size_t)bh * 4096;
#pragma unroll
  for (int j = 0; j < 2; ++j) {
    int id = t + (j << 8);
    int r = id >> 3, s = id & 7;
    u32x4 v = *(const u32x4*)(bSrc + r * 64 + (s << 3));
    *(u32x4*)(sB + r * 64 + ((s ^ (r & 7)) << 3)) = v;
  }
  if (t < 64) zsh[t] = Z[(size_t)bh * 64 + t];
  __syncthreads();

  {
    float d_ = 1e-6f;
#pragma unroll
    for (int s = 0; s < 8; ++s) {
      half8 q = *(const half8*)(sA + t * 64 + (((s ^ (t & 7))) << 3));
#pragma unroll
      for (int j = 0; j < 8; ++j)
        d_ += (float)q[j] * zsh[(s << 3) + j];
    }
    dsh[t] = d_;
  }

  int w = t >> 6, l = t & 63;
  int m16 = l & 15, qd = l >> 4;
  int wrow = w << 6;

  f32x4 acc[4][4];
#pragma unroll
  for (int i = 0; i < 4; ++i)
#pragma unroll
    for (int j = 0; j < 4; ++j) acc[i][j] = (f32x4){0.f, 0.f, 0.f, 0.f};

#pragma unroll
  for (int kk = 0; kk < 2; ++kk) {
    int ksb = (kk << 2) + qd;
    half8 af[4], bf[4];
#pragma unroll
    for (int mt = 0; mt < 4; ++mt) {
      int r = wrow + (mt << 4) + m16;
      af[mt] = *(const half8*)(sA + r * 64 + ((ksb ^ (r & 7)) << 3));
    }
#pragma unroll
    for (int nt = 0; nt < 4; ++nt) {
      int r = (nt << 4) + m16;
      bf[nt] = *(const half8*)(sB + r * 64 + ((ksb ^ (r & 7)) << 3));
    }
#pragma unroll
    for (int mt = 0; mt < 4; ++mt)
#pragma unroll
      for (int nt = 0; nt < 4; ++nt)
        acc[mt][nt] = __builtin_amdgcn_mfma_f32_16x16x32_f16(af[mt], bf[nt], acc[mt][nt], 0, 0, 0);
  }
  __syncthreads();

#pragma unroll
  for (int mt = 0; mt < 4; ++mt) {
#pragma unroll
    for (int i = 0; i < 4; ++i) {
      int rloc = wrow + (mt << 4) + (qd << 2) + i;
      float rcp = 1.f / dsh[rloc];
      size_t obase = (size_t)(tok0 + rloc) * D_MODEL + h * DH + m16;
#pragma unroll
      for (int nt = 0; nt < 4; ++nt)
        O[obase + (nt << 4)] = f2h(acc[mt][nt][i] * rcp);
    }
  }
}

extern "C" void kernel_launch(void* const* d_in, const int* in_sizes, int n_in,
                              void* d_out, int out_size, void* d_ws, size_t ws_size,
                              hipStream_t stream) {
  const float* x    = (const float*)d_in[0];
  const float* ln1g = (const float*)d_in[1];
  const float* ln1b = (const float*)d_in[2];
  const float* wq   = (const float*)d_in[3];
  const float* wk   = (const float*)d_in[4];
  const float* wv   = (const float*)d_in[5];
  const float* wo   = (const float*)d_in[6];
  const float* ln2g = (const float*)d_in[7];
  const float* ln2b = (const float*)d_in[8];
  const float* w1   = (const float*)d_in[9];
  const float* w2   = (const float*)d_in[10];
  float* out = (float*)d_out;
  char* ws = (char*)d_ws;

  const size_t MB = 1024 * 1024;
  unsigned short* xn   = (unsigned short*)(ws);
  unsigned short* qkv  = (unsigned short*)(ws + 32 * MB);  // phiq|phik|vbuf fp16
  unsigned short* phiq = qkv;
  unsigned short* phik = qkv + (size_t)NTOK * D_MODEL;
  unsigned short* vbuf = qkv + 2 * (size_t)NTOK * D_MODEL;
  unsigned short* ffn  = (unsigned short*)(ws + 32 * MB);  // overlays qkv slab
  unsigned short* w1T  = (unsigned short*)(ws + 96 * MB);
  unsigned short* w2T  = (unsigned short*)(ws + 104 * MB);
  unsigned short* woT  = (unsigned short*)(ws + 128 * MB);

  // d_out as scratch until wo-GEMM writes it
  unsigned short* wqkvT = (unsigned short*)d_out;          // [3072,1024] fp16
  float* kvP = (float*)((char*)d_out + 6 * MB);
  unsigned short* kvT16 = (unsigned short*)((char*)d_out + 24 * MB);
  float* z   = (float*)((char*)d_out + 25 * MB);

  dim3 blk(256);

  // 6 weight transposes + LN1, one launch
  prep_kernel<<<dim3(3072 + NTOK), blk, 0, stream>>>(
      wq, wk, wv, wo, w1, w2, x, ln1g, ln1b, wqkvT, woT, w1T, w2T, xn);

  // fused qkv: C[8192,3072] -> phi(q),phi(k) | v, fp16 slabs (fat tile)
  dim3 gQKV(3 * D_MODEL / 128, NTOK / 256);
  mfma_gemm_fat<4><<<gQKV, blk, 0, stream>>>(xn, wqkvT, qkv, nullptr, 3 * D_MODEL, D_MODEL);

  kvz_partial<<<dim3(KVCH, BATCH * NHEADS), blk, 0, stream>>>(phik, vbuf, kvP);
  kvz_reduce<<<dim3(BATCH * NHEADS, 4), blk, 0, stream>>>(kvP, kvT16, z);

  attn_mfma<<<dim3(NTOK / 256, NHEADS), blk, 0, stream>>>(phiq, kvT16, z, xn);

  dim3 gD(D_MODEL / 128, NTOK / 128);
  // x1 = x + attn@wo -> out  (K=1024, ~25us: keep proven BK=128 path)
  mfma_gemm<2, 128><<<gD, blk, 0, stream>>>(xn, woT, out, x, D_MODEL, D_MODEL);

  ln_kernel<<<NTOK, blk, 0, stream>>>(out, ln2g, ln2b, xn);

  // ffn = gelu_lut(xn @ w1), fp16 (fat tile)
  dim3 gF(DFF / 128, NTOK / 256);
  mfma_gemm_fat<3><<<gF, blk, 0, stream>>>(xn, w1T, ffn, nullptr, DFF, D_MODEL);

  // out += ffn @ w2  (fat tile @ 1 blk/CU: the one untried config for the
  // largest dispatch; model 55-70us vs 84.9. If >=85, revert + declare.)
  dim3 gD2(D_MODEL / 128, NTOK / 256);
  mfma_gemm_fat<2><<<gD2, blk, 0, stream>>>(ffn, w2T, out, out, D_MODEL, DFF);
}

// Round 12
// 427.666 us; speedup vs baseline: 1.1073x; 1.1073x over previous
//
#include <hip/hip_runtime.h>
#include <cstdint>
#include <cstddef>

// PiFormerBlock, MFMA fp16, round 20 (= round-18/round-10 state, the 429.5us
// session best, restored verbatim).
//   x = x + linattn(LN1(x)) @ wo ;  x = x + gelu_lut(LN2(x) @ w1) @ w2
// Round-19 falsified the last open GEMM config: fat w2 @ 1 blk/CU = 126.5us
// (MfmaUtil 21.5%, Occ 10.9%) -- 4 waves/CU cannot cover the 2-phase
// vmcnt(0)+barrier drain. w2 design space now CLOSED:
//   BK=128 @2blk = 84.9 (best) | BK=64 @2blk = +5 | split-K atomic @4blk =
//   99 | fat @1blk = 126.5. Rule: never <2 blocks/CU on a 2-phase loop.
// GEMM ledger (all counter-verified): qkv=fat<4>, w1=fat<3> (~0.375
// b128/MFMA, 2blk/CU), w2=wo=mfma_gemm<2,128> (2blk/CU). 8-phase ports
// failed 3x (r9-11); occupancy/split-K/atomics all falsified (r14-16,r19).
// Non-GEMM: prep/ln/kvz/attn at memory or launch floors (r4-r8 probes).
//
// ws layout (bytes):
//   0      xn    [8192x1024] fp16 (16MB)  (reused as attn out)
//   32MB   phiq  fp16 (16MB) \
//   48MB   phik  fp16 (16MB)  >-- contiguous qkv slab; later overlaid by
//   64MB   vbuf  fp16 (16MB) /    ffn fp16 [8192x4096] (64MB @ 32MB)
//   96MB   w1T   fp16 (8MB) | 104MB w2T fp16 (8MB) | 128MB woT fp16 (2MB)
// d_out scratch (dead before wo-GEMM writes it):
//   0MB wqkvT (6MB) | 6MB kv partials (8.5MB) | 24MB kvT16 (512KB) | 25MB z

#define D_MODEL 1024
#define SEQ     2048
#define BATCH   4
#define NTOK    8192
#define NHEADS  16
#define DH      64
#define DFF     4096
#define KVCH    8
#define CHROWS  (SEQ / KVCH)
#define PSTRIDE 4160

typedef _Float16 half8 __attribute__((ext_vector_type(8)));
typedef float f32x4 __attribute__((ext_vector_type(4)));
typedef unsigned int u32x4 __attribute__((ext_vector_type(4)));

__device__ __forceinline__ unsigned short f2h(float x) {
  _Float16 h = (_Float16)x;
  union { _Float16 h; unsigned short u; } c; c.h = h; return c.u;
}
__device__ __forceinline__ float h2f(unsigned short u) {
  union { unsigned short u; _Float16 h; } c; c.u = u; return (float)c.h;
}

__device__ __forceinline__ float phi_act(float x) {
  return x > 0.f ? x + 1.f : expf(x);
}

__device__ __forceinline__ float gelu_exact(float v) {
  float c = 0.7978845608028654f;
  float t = tanhf(c * (v + 0.044715f * v * v * v));
  return 0.5f * v * (1.f + t);
}

__device__ __forceinline__ void gl_lds16(const void* g, void* l) {
  __builtin_amdgcn_global_load_lds(
      (const __attribute__((address_space(1))) unsigned int*)g,
      (__attribute__((address_space(3))) unsigned int*)l, 16, 0, 0);
}

// ---------------- transpose-convert body: W fp32 [K,N] -> WT fp16 [N,K] ----
__device__ __forceinline__ void convT_body(const float* __restrict__ W,
                                           unsigned short* __restrict__ WT,
                                           int K, int N, int bx, int by, int t) {
  __shared__ float tile[64][65];
  int kb = by << 6, nb = bx << 6;
  int rr = t >> 4, cc = (t & 15) << 2;
#pragma unroll
  for (int i = 0; i < 4; ++i) {
    int r = rr + (i << 4);
    float4 v = *(const float4*)(W + (size_t)(kb + r) * N + nb + cc);
    tile[r][cc] = v.x; tile[r][cc + 1] = v.y; tile[r][cc + 2] = v.z; tile[r][cc + 3] = v.w;
  }
  __syncthreads();
#pragma unroll
  for (int i = 0; i < 4; ++i) {
    int n = rr + (i << 4);
    ushort4 o;
    o.x = f2h(tile[cc + 0][n]); o.y = f2h(tile[cc + 1][n]);
    o.z = f2h(tile[cc + 2][n]); o.w = f2h(tile[cc + 3][n]);
    *(ushort4*)(WT + (size_t)(nb + n) * K + kb + cc) = o;
  }
}

// ---------------- LayerNorm body -> fp16 -----------------------------------
__device__ __forceinline__ void ln_body(const float* __restrict__ X,
                                        const float* __restrict__ g,
                                        const float* __restrict__ b,
                                        unsigned short* __restrict__ Y,
                                        int tok, int t) {
  const float4* xr = (const float4*)(X + (size_t)tok * D_MODEL);
  float4 v = xr[t];
  float s  = v.x + v.y + v.z + v.w;
  float s2 = v.x * v.x + v.y * v.y + v.z * v.z + v.w * v.w;
#pragma unroll
  for (int o = 32; o > 0; o >>= 1) {
    s  += __shfl_down(s, o);
    s2 += __shfl_down(s2, o);
  }
  __shared__ float red[8];
  __shared__ float mu_s, rs_s;
  int wid = t >> 6;
  if ((t & 63) == 0) { red[wid] = s; red[wid + 4] = s2; }
  __syncthreads();
  if (t == 0) {
    float ts  = red[0] + red[1] + red[2] + red[3];
    float ts2 = red[4] + red[5] + red[6] + red[7];
    float mu  = ts * (1.f / D_MODEL);
    float var = ts2 * (1.f / D_MODEL) - mu * mu;
    mu_s = mu;
    rs_s = rsqrtf(var + 1e-5f);
  }
  __syncthreads();
  float mu = mu_s, rs = rs_s;
  float4 gv = ((const float4*)g)[t];
  float4 bv = ((const float4*)b)[t];
  ushort4 hv;
  hv.x = f2h((v.x - mu) * rs * gv.x + bv.x);
  hv.y = f2h((v.y - mu) * rs * gv.y + bv.y);
  hv.z = f2h((v.z - mu) * rs * gv.z + bv.z);
  hv.w = f2h((v.w - mu) * rs * gv.w + bv.w);
  ((ushort4*)(Y + (size_t)tok * D_MODEL))[t] = hv;
}

// ---------------- prep: 6 weight transposes + LN1 in one launch ------------
__global__ __launch_bounds__(256) void prep_kernel(
    const float* __restrict__ wq, const float* __restrict__ wk,
    const float* __restrict__ wv, const float* __restrict__ wo,
    const float* __restrict__ w1, const float* __restrict__ w2,
    const float* __restrict__ x, const float* __restrict__ g,
    const float* __restrict__ b,
    unsigned short* __restrict__ wqkvT, unsigned short* __restrict__ woT,
    unsigned short* __restrict__ w1T, unsigned short* __restrict__ w2T,
    unsigned short* __restrict__ xn) {
  int f = blockIdx.x;
  int t = threadIdx.x;
  if (f < 1024) {
    int job = f >> 8, r = f & 255;
    const float* W = (job == 0) ? wq : (job == 1) ? wk : (job == 2) ? wv : wo;
    unsigned short* D = (job == 3) ? woT
                                   : wqkvT + (size_t)job * D_MODEL * D_MODEL;
    convT_body(W, D, D_MODEL, D_MODEL, r & 15, r >> 4, t);
  } else if (f < 2048) {
    int r = f - 1024;
    convT_body(w1, w1T, D_MODEL, DFF, r & 63, r >> 6, t);
  } else if (f < 3072) {
    int r = f - 2048;
    convT_body(w2, w2T, DFF, D_MODEL, r & 15, r >> 4, t);
  } else {
    ln_body(x, g, b, xn, f - 3072, t);
  }
}

// ---------------- standalone LN (for LN2) ----------------------------------
__global__ __launch_bounds__(256) void ln_kernel(const float* __restrict__ X,
                                                 const float* __restrict__ g,
                                                 const float* __restrict__ b,
                                                 unsigned short* __restrict__ Y) {
  ln_body(X, g, b, Y, blockIdx.x, threadIdx.x);
}

// ---------------- MFMA GEMM: C[M,N] = A[M,K] @ BT[N,K]^T (fp16 in) ---------
// 128x128 tile, 4 waves @ 64x64. Kept for wo + w2 (N=1024 grids, 2 blk/CU).
template <int EP, int BK>
__global__ __launch_bounds__(256, (BK == 64) ? 4 : 2) void mfma_gemm(
    const unsigned short* __restrict__ A,
    const unsigned short* __restrict__ BT,
    void* Cv, const float* R, int N, int K) {
  constexpr int SEGS = BK / 8;
  constexpr int RPC  = 64 / SEGS;
  constexpr int NJ   = 32 / RPC;
  __shared__ unsigned short smem[2 * 128 * BK];
  __shared__ float gtab[EP == 3 ? 256 : 1];
  unsigned short* sA = smem;
  unsigned short* sB = smem + 128 * BK;

  int t = threadIdx.x;
  if (EP == 3) gtab[t & 255] = gelu_exact((float)((t & 255) - 128) * 0.1f);

  int bm, bn;
  {
    int L = blockIdx.y * gridDim.x + blockIdx.x;
    if ((gridDim.y & 7) == 0) {
      int xcd = L & 7, wi = L >> 3;
      int mPerX = gridDim.y >> 3;
      bm = xcd * mPerX + wi / gridDim.x;
      bn = wi % gridDim.x;
    } else {
      bn = blockIdx.x; bm = blockIdx.y;
    }
  }

  int w = t >> 6, l = t & 63;
  int lrow = l / SEGS;
  int lseg = l & (SEGS - 1);
  int m0 = bm << 7;
  int n0 = bn << 7;
  size_t strideB = (size_t)K * 2;

  const char* gA[NJ]; const char* gB[NJ];
  int ldsOff[NJ];
#pragma unroll
  for (int j = 0; j < NJ; ++j) {
    int row = (w << 5) + j * RPC + lrow;
    int gso = (lseg ^ (row & 7)) << 4;
    gA[j] = (const char*)A + (size_t)(m0 + row) * strideB + gso;
    gB[j] = (const char*)BT + (size_t)(n0 + row) * strideB + gso;
    ldsOff[j] = ((w << 5) + j * RPC) * BK;
  }

  int wm = w >> 1, wn = w & 1;
  int m16 = l & 15, qd = l >> 4;

  f32x4 acc[4][4];
#pragma unroll
  for (int i = 0; i < 4; ++i)
#pragma unroll
    for (int j = 0; j < 4; ++j) acc[i][j] = (f32x4){0.f, 0.f, 0.f, 0.f};

  for (int k0 = 0; k0 < K; k0 += BK) {
    size_t kb = (size_t)k0 * 2;
#pragma unroll
    for (int j = 0; j < NJ; ++j) {
      gl_lds16(gA[j] + kb, sA + ldsOff[j]);
      gl_lds16(gB[j] + kb, sB + ldsOff[j]);
    }
    __syncthreads();
#pragma unroll
    for (int kk = 0; kk < BK / 32; ++kk) {
      int ksb = (kk << 2) + qd;
      half8 af[4], bf[4];
#pragma unroll
      for (int mt = 0; mt < 4; ++mt) {
        int r = (wm << 6) + (mt << 4) + m16;
        int slot = ksb ^ (r & 7);
        af[mt] = *(const half8*)(sA + r * BK + (slot << 3));
      }
#pragma unroll
      for (int nt = 0; nt < 4; ++nt) {
        int r = (wn << 6) + (nt << 4) + m16;
        int slot = ksb ^ (r & 7);
        bf[nt] = *(const half8*)(sB + r * BK + (slot << 3));
      }
#pragma unroll
      for (int mt = 0; mt < 4; ++mt)
#pragma unroll
        for (int nt = 0; nt < 4; ++nt)
          acc[mt][nt] = __builtin_amdgcn_mfma_f32_16x16x32_f16(af[mt], bf[nt], acc[mt][nt], 0, 0, 0);
    }
    __syncthreads();
  }

  int colBase = n0 + (wn << 6) + m16;
#pragma unroll
  for (int mt = 0; mt < 4; ++mt) {
    int rBase = m0 + (wm << 6) + (mt << 4) + (qd << 2);
#pragma unroll
    for (int nt = 0; nt < 4; ++nt) {
      int col = colBase + (nt << 4);
#pragma unroll
      for (int i = 0; i < 4; ++i) {
        float v = acc[mt][nt][i];
        size_t idx = (size_t)(rBase + i) * N + col;
        if (EP == 2)      ((float*)Cv)[idx] = R[idx] + v;
        else if (EP == 3) {
          float r = rintf(v / 0.1f);
          int iq = (int)r + 128;
          iq = iq < 0 ? 0 : (iq > 255 ? 255 : iq);
          ((unsigned short*)Cv)[idx] = f2h(gtab[iq]);
        } else          ((float*)Cv)[idx] = v;
      }
    }
  }
}

// ---------------- FAT MFMA GEMM: 256x128 tile, 4 waves @ 128x64 ------------
// 24 b128 per 64 MFMA = 0.375 b128/MFMA (-25% LDS/FLOP vs 64x64 wave tile).
// acc 8x4 (~200 VGPR, launch_bounds(256,2)); LDS 48KB -> 2 blk/CU at grids
// >= 512 blocks. BK=64. EP: 3 gelu-LUT (w1) | 4 fused qkv.
template <int EP>
__global__ __launch_bounds__(256, 2) void mfma_gemm_fat(
    const unsigned short* __restrict__ A,
    const unsigned short* __restrict__ BT,
    void* Cv, int N, int K) {
  constexpr int BK = 64;
  __shared__ unsigned short sA[256 * BK];   // 32 KB
  __shared__ unsigned short sB[128 * BK];   // 16 KB
  __shared__ float gtab[EP == 3 ? 256 : 1];

  int t = threadIdx.x;
  if (EP == 3) gtab[t & 255] = gelu_exact((float)((t & 255) - 128) * 0.1f);

  int bm, bn;
  {
    int L = blockIdx.y * gridDim.x + blockIdx.x;
    if ((gridDim.y & 7) == 0) {                 // NTOK/256 = 32 -> true
      int xcd = L & 7, wi = L >> 3;
      int mPerX = gridDim.y >> 3;
      bm = xcd * mPerX + wi / gridDim.x;
      bn = wi % gridDim.x;
    } else {
      bn = blockIdx.x; bm = blockIdx.y;
    }
  }
  int m0 = bm << 8, n0 = bn << 7;

  int w = t >> 6, l = t & 63;
  int lrow = l >> 3;          // SEGS = 8
  int lseg = l & 7;
  size_t strideB = (size_t)K * 2;
  size_t rstep8 = (size_t)8 * strideB;        // 8 rows of global stride

  // staging bases: wave w owns A rows [w*64, +64) (8 calls), B rows [w*32,+32) (4)
  int rowA0 = (w << 6) + lrow;
  int rowB0 = (w << 5) + lrow;
  const char* gA0 = (const char*)A  + (size_t)(m0 + rowA0) * strideB + ((lseg ^ (rowA0 & 7)) << 4);
  const char* gB0 = (const char*)BT + (size_t)(n0 + rowB0) * strideB + ((lseg ^ (rowB0 & 7)) << 4);
  // (rowA0+8j)&7 == rowA0&7 -> same swizzled seg offset for all j
  int ldsA0 = ((w << 6)) * BK;                // shorts; +j*512
  int ldsB0 = ((w << 5)) * BK;

  int wm = w >> 1, wn = w & 1;
  int m16 = l & 15, qd = l >> 4;

  f32x4 acc[8][4];
#pragma unroll
  for (int i = 0; i < 8; ++i)
#pragma unroll
    for (int j = 0; j < 4; ++j) acc[i][j] = (f32x4){0.f, 0.f, 0.f, 0.f};

  for (int k0 = 0; k0 < K; k0 += BK) {
    size_t kb = (size_t)k0 * 2;
#pragma unroll
    for (int j = 0; j < 8; ++j)
      gl_lds16(gA0 + kb + j * rstep8, sA + ldsA0 + j * 512);
#pragma unroll
    for (int j = 0; j < 4; ++j)
      gl_lds16(gB0 + kb + j * rstep8, sB + ldsB0 + j * 512);
    __syncthreads();
#pragma unroll
    for (int kk = 0; kk < 2; ++kk) {
      int ksb = (kk << 2) + qd;
      half8 af[8], bf[4];
#pragma unroll
      for (int mt = 0; mt < 8; ++mt) {
        int r = (wm << 7) + (mt << 4) + m16;
        af[mt] = *(const half8*)(sA + r * BK + ((ksb ^ (r & 7)) << 3));
      }
#pragma unroll
      for (int nt = 0; nt < 4; ++nt) {
        int r = (wn << 6) + (nt << 4) + m16;
        bf[nt] = *(const half8*)(sB + r * BK + ((ksb ^ (r & 7)) << 3));
      }
#pragma unroll
      for (int mt = 0; mt < 8; ++mt)
#pragma unroll
        for (int nt = 0; nt < 4; ++nt)
          acc[mt][nt] = __builtin_amdgcn_mfma_f32_16x16x32_f16(af[mt], bf[nt], acc[mt][nt], 0, 0, 0);
    }
    __syncthreads();
  }

  // epilogue
  int sel = n0 >> 10;                       // EP=4: 0=q 1=k 2=v
  size_t slab = (size_t)sel * ((size_t)NTOK * D_MODEL);
  int colL = (n0 & 1023) + (wn << 6) + m16;
  int colBase = n0 + (wn << 6) + m16;
#pragma unroll
  for (int mt = 0; mt < 8; ++mt) {
    int rBase = m0 + (wm << 7) + (mt << 4) + (qd << 2);
#pragma unroll
    for (int nt = 0; nt < 4; ++nt) {
#pragma unroll
      for (int i = 0; i < 4; ++i) {
        float v = acc[mt][nt][i];
        if (EP == 4) {
          if (sel < 2) v = phi_act(v);
          size_t idx = slab + (size_t)(rBase + i) * D_MODEL + colL + (nt << 4);
          ((unsigned short*)Cv)[idx] = f2h(v);
        } else {  // EP == 3
          float r = rintf(v / 0.1f);
          int iq = (int)r + 128;
          iq = iq < 0 ? 0 : (iq > 255 ? 255 : iq);
          ((unsigned short*)Cv)[(size_t)(rBase + i) * N + colBase + (nt << 4)] = f2h(gtab[iq]);
        }
      }
    }
  }
}

// ---------------- stage 1: partial kv/z over an S-chunk (fp16 in) ----------
__global__ __launch_bounds__(256) void kvz_partial(const unsigned short* __restrict__ PK,
                                                   const unsigned short* __restrict__ V,
                                                   float* __restrict__ P) {
  int c = blockIdx.x, bh = blockIdx.y;
  int b = bh >> 4, h = bh & 15;
  __shared__ float pk[8][64];
  __shared__ float vv[8][64];
  int t = threadIdx.x;
  const size_t base = ((size_t)b * SEQ + (size_t)c * CHROWS) * D_MODEL + h * DH;
  int u = t & 127;
  int lrow = u >> 4;
  int lcol = (u & 15) << 2;
  bool isV = (t >= 128);
  const unsigned short* src = isV ? V : PK;
  int dkb = (t >> 4) << 2;
  int deb = (t & 15) << 2;
  float acc[4][4] = {};
  float zacc = 0.f;
  for (int s0 = 0; s0 < CHROWS; s0 += 8) {
    ushort4 ld = *(const ushort4*)(src + base + (size_t)(s0 + lrow) * D_MODEL + lcol);
    float f0 = h2f(ld.x), f1 = h2f(ld.y), f2 = h2f(ld.z), f3 = h2f(ld.w);
    __syncthreads();
    if (isV) { vv[lrow][lcol] = f0; vv[lrow][lcol+1] = f1; vv[lrow][lcol+2] = f2; vv[lrow][lcol+3] = f3; }
    else     { pk[lrow][lcol] = f0; pk[lrow][lcol+1] = f1; pk[lrow][lcol+2] = f2; pk[lrow][lcol+3] = f3; }
    __syncthreads();
#pragma unroll
    for (int ss = 0; ss < 8; ++ss) {
      float4 a  = *(const float4*)&pk[ss][dkb];
      float4 bb = *(const float4*)&vv[ss][deb];
      acc[0][0] += a.x * bb.x; acc[0][1] += a.x * bb.y; acc[0][2] += a.x * bb.z; acc[0][3] += a.x * bb.w;
      acc[1][0] += a.y * bb.x; acc[1][1] += a.y * bb.y; acc[1][2] += a.y * bb.z; acc[1][3] += a.y * bb.w;
      acc[2][0] += a.z * bb.x; acc[2][1] += a.z * bb.y; acc[2][2] += a.z * bb.z; acc[2][3] += a.z * bb.w;
      acc[3][0] += a.w * bb.x; acc[3][1] += a.w * bb.y; acc[3][2] += a.w * bb.z; acc[3][3] += a.w * bb.w;
    }
    if (t < 64) {
#pragma unroll
      for (int ss = 0; ss < 8; ++ss) zacc += pk[ss][t];
    }
  }
  float* Pb = P + ((size_t)c * 64 + bh) * PSTRIDE;
#pragma unroll
  for (int i = 0; i < 4; ++i) {
    float4 o; o.x = acc[i][0]; o.y = acc[i][1]; o.z = acc[i][2]; o.w = acc[i][3];
    *(float4*)(Pb + (size_t)(dkb + i) * DH + deb) = o;
  }
  if (t < 64) Pb[4096 + t] = zacc;
}

// ---------------- stage 2: reduce partials -> kvT fp16 [e][d] + z fp32 -----
// grid (64 bh, 4): quarter q handles elements [q*1040, (q+1)*1040).
__global__ __launch_bounds__(256) void kvz_reduce(const float* __restrict__ P,
                                                  unsigned short* __restrict__ KVT,
                                                  float* __restrict__ Z) {
  int bh = blockIdx.x;
  int q = blockIdx.y;
  int t = threadIdx.x;
  int lo = q * (PSTRIDE / 4), hi = lo + (PSTRIDE / 4);
  for (int i = lo + t; i < hi; i += 256) {
    float s = 0.f;
#pragma unroll
    for (int c = 0; c < KVCH; ++c)
      s += P[((size_t)c * 64 + bh) * PSTRIDE + i];
    if (i < 4096) {
      int d = i >> 6, e = i & 63;
      KVT[(size_t)bh * 4096 + e * 64 + d] = f2h(s);   // BT layout [e][d]
    } else {
      Z[(size_t)bh * 64 + (i - 4096)] = s;
    }
  }
}

// ---------------- attn via MFMA: out = (phiq @ kv) / (phiq.z) --------------
__global__ __launch_bounds__(256) void attn_mfma(const unsigned short* __restrict__ PQ,
                                                 const unsigned short* __restrict__ KVT,
                                                 const float* __restrict__ Z,
                                                 unsigned short* __restrict__ O) {
  __shared__ unsigned short sA[256 * 64];   // 32 KB, swizzled
  __shared__ unsigned short sB[64 * 64];    // 8 KB, swizzled
  __shared__ float zsh[64];
  __shared__ float dsh[256];
  int t = threadIdx.x;
  int tok0 = blockIdx.x << 8;
  int h = blockIdx.y;
  int b = tok0 >> 11;                       // SEQ=2048
  int bh = b * NHEADS + h;

  const unsigned short* aSrc = PQ + (size_t)tok0 * D_MODEL + h * DH;
#pragma unroll
  for (int j = 0; j < 8; ++j) {
    int id = t + (j << 8);
    int r = id >> 3, s = id & 7;
    u32x4 v = *(const u32x4*)(aSrc + (size_t)r * D_MODEL + (s << 3));
    *(u32x4*)(sA + r * 64 + ((s ^ (r & 7)) << 3)) = v;
  }
  const unsigned short* bSrc = KVT + (size_t)bh * 4096;
#pragma unroll
  for (int j = 0; j < 2; ++j) {
    int id = t + (j << 8);
    int r = id >> 3, s = id & 7;
    u32x4 v = *(const u32x4*)(bSrc + r * 64 + (s << 3));
    *(u32x4*)(sB + r * 64 + ((s ^ (r & 7)) << 3)) = v;
  }
  if (t < 64) zsh[t] = Z[(size_t)bh * 64 + t];
  __syncthreads();

  {
    float d_ = 1e-6f;
#pragma unroll
    for (int s = 0; s < 8; ++s) {
      half8 q = *(const half8*)(sA + t * 64 + (((s ^ (t & 7))) << 3));
#pragma unroll
      for (int j = 0; j < 8; ++j)
        d_ += (float)q[j] * zsh[(s << 3) + j];
    }
    dsh[t] = d_;
  }

  int w = t >> 6, l = t & 63;
  int m16 = l & 15, qd = l >> 4;
  int wrow = w << 6;

  f32x4 acc[4][4];
#pragma unroll
  for (int i = 0; i < 4; ++i)
#pragma unroll
    for (int j = 0; j < 4; ++j) acc[i][j] = (f32x4){0.f, 0.f, 0.f, 0.f};

#pragma unroll
  for (int kk = 0; kk < 2; ++kk) {
    int ksb = (kk << 2) + qd;
    half8 af[4], bf[4];
#pragma unroll
    for (int mt = 0; mt < 4; ++mt) {
      int r = wrow + (mt << 4) + m16;
      af[mt] = *(const half8*)(sA + r * 64 + ((ksb ^ (r & 7)) << 3));
    }
#pragma unroll
    for (int nt = 0; nt < 4; ++nt) {
      int r = (nt << 4) + m16;
      bf[nt] = *(const half8*)(sB + r * 64 + ((ksb ^ (r & 7)) << 3));
    }
#pragma unroll
    for (int mt = 0; mt < 4; ++mt)
#pragma unroll
      for (int nt = 0; nt < 4; ++nt)
        acc[mt][nt] = __builtin_amdgcn_mfma_f32_16x16x32_f16(af[mt], bf[nt], acc[mt][nt], 0, 0, 0);
  }
  __syncthreads();

#pragma unroll
  for (int mt = 0; mt < 4; ++mt) {
#pragma unroll
    for (int i = 0; i < 4; ++i) {
      int rloc = wrow + (mt << 4) + (qd << 2) + i;
      float rcp = 1.f / dsh[rloc];
      size_t obase = (size_t)(tok0 + rloc) * D_MODEL + h * DH + m16;
#pragma unroll
      for (int nt = 0; nt < 4; ++nt)
        O[obase + (nt << 4)] = f2h(acc[mt][nt][i] * rcp);
    }
  }
}

extern "C" void kernel_launch(void* const* d_in, const int* in_sizes, int n_in,
                              void* d_out, int out_size, void* d_ws, size_t ws_size,
                              hipStream_t stream) {
  const float* x    = (const float*)d_in[0];
  const float* ln1g = (const float*)d_in[1];
  const float* ln1b = (const float*)d_in[2];
  const float* wq   = (const float*)d_in[3];
  const float* wk   = (const float*)d_in[4];
  const float* wv   = (const float*)d_in[5];
  const float* wo   = (const float*)d_in[6];
  const float* ln2g = (const float*)d_in[7];
  const float* ln2b = (const float*)d_in[8];
  const float* w1   = (const float*)d_in[9];
  const float* w2   = (const float*)d_in[10];
  float* out = (float*)d_out;
  char* ws = (char*)d_ws;

  const size_t MB = 1024 * 1024;
  unsigned short* xn   = (unsigned short*)(ws);
  unsigned short* qkv  = (unsigned short*)(ws + 32 * MB);  // phiq|phik|vbuf fp16
  unsigned short* phiq = qkv;
  unsigned short* phik = qkv + (size_t)NTOK * D_MODEL;
  unsigned short* vbuf = qkv + 2 * (size_t)NTOK * D_MODEL;
  unsigned short* ffn  = (unsigned short*)(ws + 32 * MB);  // overlays qkv slab
  unsigned short* w1T  = (unsigned short*)(ws + 96 * MB);
  unsigned short* w2T  = (unsigned short*)(ws + 104 * MB);
  unsigned short* woT  = (unsigned short*)(ws + 128 * MB);

  // d_out as scratch until wo-GEMM writes it
  unsigned short* wqkvT = (unsigned short*)d_out;          // [3072,1024] fp16
  float* kvP = (float*)((char*)d_out + 6 * MB);
  unsigned short* kvT16 = (unsigned short*)((char*)d_out + 24 * MB);
  float* z   = (float*)((char*)d_out + 25 * MB);

  dim3 blk(256);

  // 6 weight transposes + LN1, one launch
  prep_kernel<<<dim3(3072 + NTOK), blk, 0, stream>>>(
      wq, wk, wv, wo, w1, w2, x, ln1g, ln1b, wqkvT, woT, w1T, w2T, xn);

  // fused qkv: C[8192,3072] -> phi(q),phi(k) | v, fp16 slabs (fat tile)
  dim3 gQKV(3 * D_MODEL / 128, NTOK / 256);
  mfma_gemm_fat<4><<<gQKV, blk, 0, stream>>>(xn, wqkvT, qkv, 3 * D_MODEL, D_MODEL);

  kvz_partial<<<dim3(KVCH, BATCH * NHEADS), blk, 0, stream>>>(phik, vbuf, kvP);
  kvz_reduce<<<dim3(BATCH * NHEADS, 4), blk, 0, stream>>>(kvP, kvT16, z);

  attn_mfma<<<dim3(NTOK / 256, NHEADS), blk, 0, stream>>>(phiq, kvT16, z, xn);

  dim3 gD(D_MODEL / 128, NTOK / 128);
  // x1 = x + attn@wo -> out  (K=1024: proven BK=128 path)
  mfma_gemm<2, 128><<<gD, blk, 0, stream>>>(xn, woT, out, x, D_MODEL, D_MODEL);

  ln_kernel<<<NTOK, blk, 0, stream>>>(out, ln2g, ln2b, xn);

  // ffn = gelu_lut(xn @ w1), fp16 (fat tile)
  dim3 gF(DFF / 128, NTOK / 256);
  mfma_gemm_fat<3><<<gF, blk, 0, stream>>>(xn, w1T, ffn, DFF, D_MODEL);

  // out += ffn @ w2  (BK=128 @ 2 blk/CU: best of the closed design space)
  mfma_gemm<2, 128><<<gD, blk, 0, stream>>>(ffn, w2T, out, out, D_MODEL, DFF);
}